// Round 1
// baseline (1995.658 us; speedup 1.0000x reference)
//
#include <hip/hip_runtime.h>
#include <math.h>

// ---------------------------------------------------------------------------
// B=4096, IN=10338 (pad 10368), H=1024, OUT=229 (pad 256)
// R8: layer-1 GEMM rewritten as 256x256/BK32, 8-wave, counted-vmcnt schedule
//     (T3+T4 from m201/m218: raw s_barrier + vmcnt(8), loads never drained in
//     the steady-state loop) + setprio around MFMA clusters (T5).
//     Mids/head keep the R7 gemm_sk (128^2, S=1 fused stats) unchanged.
//     Split-K=4 for layer 1 -> 256 blocks = 1/CU; extra partials aliased onto
//     Y/Hf so workspace footprint is unchanged.
// ---------------------------------------------------------------------------

typedef _Float16 half8 __attribute__((ext_vector_type(8)));
typedef _Float16 half4_t __attribute__((ext_vector_type(4)));
typedef float floatx4 __attribute__((ext_vector_type(4)));

#define LO_SCALE 4096.0f
#define LO_INV (1.0f / 4096.0f)
#define IN_C 10338
#define INP_C 10368

__device__ __forceinline__ void gld16(const _Float16* g, _Float16* l) {
  __builtin_amdgcn_global_load_lds(
      (const __attribute__((address_space(1))) void*)g,
      (__attribute__((address_space(3))) void*)l, 16, 0, 0);
}

// ---------------------------------------------------------------------------
// Layer-1 GEMM: 256x256 tile, BK=32, 512 threads (8 waves, 2M x 4N).
// f16 hi/lo split (lo prescaled by 4096). Counted-vmcnt pipeline:
//   per tile: lgkmcnt(0); barrier; issue 8 gld16 (t+1); vmcnt(8); barrier;
//   then 4 phases of {ds_read A-pair; 24 MFMA} with B frags register-held.
// Steady state never drains vmcnt (T4) -- the m97-structure's ~20% barrier
// stall is the thing this removes.
// ---------------------------------------------------------------------------
__global__ __launch_bounds__(512, 2)
void gemm_l1(const _Float16* __restrict__ Ah, const _Float16* __restrict__ Al,
             const _Float16* __restrict__ Bh, const _Float16* __restrict__ Bl,
             float* __restrict__ Cp, int Kld, int Ncols, int Ks,
             size_t partStride) {
  __shared__ _Float16 sAh[2][8192], sAl[2][8192];
  __shared__ _Float16 sBh[2][8192], sBl[2][8192];
  const int tid = threadIdx.x;
  const int wv = tid >> 6, ln = tid & 63;
  const int ln15 = ln & 15, q = ln >> 4;
  const int wr = wv >> 2, wc = wv & 3;
  // XCD k owns M-panels {2k, 2k+1} (A-panel L2/L3 locality)
  const int xm = (blockIdx.x & 7) * 2 + (blockIdx.x >> 3);
  const int bm0 = xm * 256, bn0 = blockIdx.y * 256;
  const int k0 = blockIdx.z * Ks;
  Cp += (size_t)blockIdx.z * partStride;

  // staging: source-permuted so fixed lane->LDS placement yields XOR-swizzle
  // (identical scheme to R7; read-side b128 pattern is bank-minimal)
  const int srow = ln >> 2;
  const int swzw = (ln & 3) ^ (srow & 3) ^ ((srow >> 2) & 3);
  const int ch0 = wv, ch1 = wv + 8;  // 16 channels x 16 rows = 256 rows
  const size_t offA0 = (size_t)(bm0 + ch0 * 16 + srow) * Kld + k0 + swzw * 8;
  const size_t offA1 = (size_t)(bm0 + ch1 * 16 + srow) * Kld + k0 + swzw * 8;
  const size_t offB0 = (size_t)(bn0 + ch0 * 16 + srow) * Kld + k0 + swzw * 8;
  const size_t offB1 = (size_t)(bn0 + ch1 * 16 + srow) * Kld + k0 + swzw * 8;

  // fragment reads: de-swizzle
  const int swzr = (q ^ (ln15 & 3) ^ ((ln15 >> 2) & 3)) * 8;

  floatx4 acc[8][4], acc2[8][4];
#pragma unroll
  for (int i = 0; i < 8; ++i)
#pragma unroll
    for (int j = 0; j < 4; ++j) {
      acc[i][j] = (floatx4){0.f, 0.f, 0.f, 0.f};
      acc2[i][j] = (floatx4){0.f, 0.f, 0.f, 0.f};
    }

  auto stage = [&](int kt, int buf) {
    gld16(Bh + offB0 + kt, &sBh[buf][ch0 * 512]);
    gld16(Bh + offB1 + kt, &sBh[buf][ch1 * 512]);
    gld16(Bl + offB0 + kt, &sBl[buf][ch0 * 512]);
    gld16(Bl + offB1 + kt, &sBl[buf][ch1 * 512]);
    gld16(Ah + offA0 + kt, &sAh[buf][ch0 * 512]);
    gld16(Ah + offA1 + kt, &sAh[buf][ch1 * 512]);
    gld16(Al + offA0 + kt, &sAl[buf][ch0 * 512]);
    gld16(Al + offA1 + kt, &sAl[buf][ch1 * 512]);
  };

  stage(0, 0);
  int cur = 0;
  for (int kt = 0; kt < Ks; kt += 32) {
    // barrier A: own LDS reads retired, then all waves done with buf[cur^1]
    asm volatile("s_waitcnt lgkmcnt(0)" ::: "memory");
    __builtin_amdgcn_s_barrier();
    __builtin_amdgcn_sched_barrier(0);
    if (kt + 32 < Ks) {
      stage(kt + 32, cur ^ 1);  // 8 loads in flight across the whole tile
      asm volatile("s_waitcnt vmcnt(8)" ::: "memory");  // tile t landed (own)
    } else {
      asm volatile("s_waitcnt vmcnt(0)" ::: "memory");  // epilogue drain
    }
    __builtin_amdgcn_s_barrier();  // barrier B: everyone's tile-t data landed
    __builtin_amdgcn_sched_barrier(0);

    const _Float16* pAh = &sAh[cur][0];
    const _Float16* pAl = &sAl[cur][0];
    const _Float16* pBh = &sBh[cur][0];
    const _Float16* pBl = &sBl[cur][0];
    half8 bhf[4], blf[4];
#pragma unroll
    for (int ni = 0; ni < 4; ++ni) {
      const int bo = (wc * 64 + ni * 16 + ln15) * 32 + swzr;
      bhf[ni] = *(const half8*)(pBh + bo);
      blf[ni] = *(const half8*)(pBl + bo);
    }
#pragma unroll
    for (int mp = 0; mp < 4; ++mp) {
      half8 ahf[2], alf[2];
#pragma unroll
      for (int i = 0; i < 2; ++i) {
        const int ao = (wr * 128 + (mp * 2 + i) * 16 + ln15) * 32 + swzr;
        ahf[i] = *(const half8*)(pAh + ao);
        alf[i] = *(const half8*)(pAl + ao);
      }
      __builtin_amdgcn_s_setprio(1);
#pragma unroll
      for (int i = 0; i < 2; ++i) {
        const int mi = mp * 2 + i;
#pragma unroll
        for (int ni = 0; ni < 4; ++ni) {
          acc[mi][ni] = __builtin_amdgcn_mfma_f32_16x16x32_f16(
              ahf[i], bhf[ni], acc[mi][ni], 0, 0, 0);
          acc2[mi][ni] = __builtin_amdgcn_mfma_f32_16x16x32_f16(
              ahf[i], blf[ni], acc2[mi][ni], 0, 0, 0);
        }
      }
      // dependent second acc2 write sits >=8 MFMAs after the first
#pragma unroll
      for (int i = 0; i < 2; ++i) {
        const int mi = mp * 2 + i;
#pragma unroll
        for (int ni = 0; ni < 4; ++ni)
          acc2[mi][ni] = __builtin_amdgcn_mfma_f32_16x16x32_f16(
              alf[i], bhf[ni], acc2[mi][ni], 0, 0, 0);
      }
      __builtin_amdgcn_s_setprio(0);
    }
    cur ^= 1;
  }

  // C/D layout: col = lane&15, row = (lane>>4)*4 + reg  [m89-verified]
#pragma unroll
  for (int mi = 0; mi < 8; ++mi)
#pragma unroll
    for (int ni = 0; ni < 4; ++ni) {
      const int col = bn0 + wc * 64 + ni * 16 + ln15;
      const int rbase = bm0 + wr * 128 + mi * 16 + q * 4;
#pragma unroll
      for (int r = 0; r < 4; ++r)
        Cp[(size_t)(rbase + r) * Ncols + col] =
            acc[mi][ni][r] + acc2[mi][ni][r] * LO_INV;
    }
}

// C_partial[z] = A[M x Ks] * BT[N x Ks]^T  (f16 hi/lo, lo prescaled by 4096)
// 128^2 tile, 4 waves. Kept for mids (S=1 fused bias+stats) and head.
template <int TAG, bool STATS>
__global__ __launch_bounds__(256, 2)
void gemm_sk(const _Float16* __restrict__ Ah, const _Float16* __restrict__ Al,
             const _Float16* __restrict__ Bh, const _Float16* __restrict__ Bl,
             float* __restrict__ Cp, int Kld, int Ncols, int Ks,
             size_t partStride, const float* __restrict__ bias,
             float* __restrict__ psum, float* __restrict__ psq) {
  __shared__ _Float16 sAh[2][4096], sAl[2][4096];
  __shared__ _Float16 sBh[2][4096], sBl[2][4096];
  const int tid = threadIdx.x;
  const int wv = tid >> 6, ln = tid & 63;
  const int ln15 = ln & 15, q = ln >> 4;
  const int wr = wv >> 1, wc = wv & 1;
  const int bm0 = blockIdx.x * 128, bn0 = blockIdx.y * 128;
  const int k0 = blockIdx.z * Ks;
  Cp += (size_t)blockIdx.z * partStride;

  const int srow = ln >> 2;
  const int swzw = (ln & 3) ^ (srow & 3) ^ ((srow >> 2) & 3);
  const int ch0 = wv * 2, ch1 = wv * 2 + 1;
  const size_t offA0 = (size_t)(bm0 + ch0 * 16 + srow) * Kld + k0 + swzw * 8;
  const size_t offA1 = (size_t)(bm0 + ch1 * 16 + srow) * Kld + k0 + swzw * 8;
  const size_t offB0 = (size_t)(bn0 + ch0 * 16 + srow) * Kld + k0 + swzw * 8;
  const size_t offB1 = (size_t)(bn0 + ch1 * 16 + srow) * Kld + k0 + swzw * 8;

  const int swzr = (q ^ (ln15 & 3) ^ ((ln15 >> 2) & 3)) * 8;
  const int aoff = (wr * 64 + ln15) * 32 + swzr;
  const int boff = (wc * 64 + ln15) * 32 + swzr;

  floatx4 acc[4][4];
  floatx4 acc2[4][4];
#pragma unroll
  for (int i = 0; i < 4; ++i)
#pragma unroll
    for (int j = 0; j < 4; ++j) {
      acc[i][j] = (floatx4){0.f, 0.f, 0.f, 0.f};
      acc2[i][j] = (floatx4){0.f, 0.f, 0.f, 0.f};
    }

  auto stage = [&](int kt, int buf) {
    gld16(Ah + offA0 + kt, &sAh[buf][ch0 * 512]);
    gld16(Ah + offA1 + kt, &sAh[buf][ch1 * 512]);
    gld16(Al + offA0 + kt, &sAl[buf][ch0 * 512]);
    gld16(Al + offA1 + kt, &sAl[buf][ch1 * 512]);
    gld16(Bh + offB0 + kt, &sBh[buf][ch0 * 512]);
    gld16(Bh + offB1 + kt, &sBh[buf][ch1 * 512]);
    gld16(Bl + offB0 + kt, &sBl[buf][ch0 * 512]);
    gld16(Bl + offB1 + kt, &sBl[buf][ch1 * 512]);
  };

  stage(0, 0);
  int cur = 0;
  for (int kt = 0; kt < Ks; kt += 32) {
    __syncthreads();
    if (kt + 32 < Ks) stage(kt + 32, cur ^ 1);

    const _Float16* pAh = &sAh[cur][aoff];
    const _Float16* pAl = &sAl[cur][aoff];
    const _Float16* pBh = &sBh[cur][boff];
    const _Float16* pBl = &sBl[cur][boff];
    half8 bh[4], bl[4];
#pragma unroll
    for (int ni = 0; ni < 4; ++ni) {
      bh[ni] = *(const half8*)(pBh + ni * 512);
      bl[ni] = *(const half8*)(pBl + ni * 512);
    }
#pragma unroll
    for (int mh = 0; mh < 2; ++mh) {
      half8 ah[2], al[2];
#pragma unroll
      for (int i = 0; i < 2; ++i) {
        ah[i] = *(const half8*)(pAh + (mh * 2 + i) * 512);
        al[i] = *(const half8*)(pAl + (mh * 2 + i) * 512);
      }
#pragma unroll
      for (int i = 0; i < 2; ++i) {
        const int mi = mh * 2 + i;
#pragma unroll
        for (int ni = 0; ni < 4; ++ni) {
          acc[mi][ni] = __builtin_amdgcn_mfma_f32_16x16x32_f16(
              ah[i], bh[ni], acc[mi][ni], 0, 0, 0);
          acc2[mi][ni] = __builtin_amdgcn_mfma_f32_16x16x32_f16(
              ah[i], bl[ni], acc2[mi][ni], 0, 0, 0);
          acc2[mi][ni] = __builtin_amdgcn_mfma_f32_16x16x32_f16(
              al[i], bh[ni], acc2[mi][ni], 0, 0, 0);
        }
      }
    }
    cur ^= 1;
  }

  // C/D layout: col = lane&15, row = (lane>>4)*4 + reg  [m89-verified]
  float bs[4];
  float sacc[4] = {0.f, 0.f, 0.f, 0.f};
  float qacc[4] = {0.f, 0.f, 0.f, 0.f};
  if constexpr (STATS) {
#pragma unroll
    for (int ni = 0; ni < 4; ++ni)
      bs[ni] = bias[bn0 + wc * 64 + ni * 16 + ln15];
  }
#pragma unroll
  for (int mi = 0; mi < 4; ++mi)
#pragma unroll
    for (int ni = 0; ni < 4; ++ni) {
      const int col = bn0 + wc * 64 + ni * 16 + ln15;
      const int rbase = bm0 + wr * 64 + mi * 16 + q * 4;
#pragma unroll
      for (int r = 0; r < 4; ++r) {
        float v = acc[mi][ni][r] + acc2[mi][ni][r] * LO_INV;
        if constexpr (STATS) {
          v += bs[ni];
          sacc[ni] += v;
          qacc[ni] += v * v;
        }
        Cp[(size_t)(rbase + r) * Ncols + col] = v;
      }
    }
  if constexpr (STATS) {
    // reuse staging LDS as scratch: 8 contributors x 128 cols
    __syncthreads();  // all waves done reading staging LDS
    float* sS = (float*)&sAh[0][0];
    float* sQ = (float*)&sAl[0][0];
    const int contrib = wr * 4 + q;  // 0..7
#pragma unroll
    for (int ni = 0; ni < 4; ++ni) {
      const int colt = wc * 64 + ni * 16 + ln15;
      sS[contrib * 128 + colt] = sacc[ni];
      sQ[contrib * 128 + colt] = qacc[ni];
    }
    __syncthreads();
    if (tid < 128) {
      float S = 0.f, Q = 0.f;
#pragma unroll
      for (int c = 0; c < 8; ++c) {
        S += sS[c * 128 + tid];
        Q += sQ[c * 128 + tid];
      }
      psum[(size_t)blockIdx.x * 1024 + bn0 + tid] = S;
      psq[(size_t)blockIdx.x * 1024 + bn0 + tid] = Q;
    }
  }
}

// ---- all conversions in one kernel ----
struct TJob {
  const float* src;
  _Float16* th;
  _Float16* tl;
  int K, N, Kpad, tK, start;
};
struct CJobs {
  TJob j[6];
  const float* x;
  _Float16* xh;
  _Float16* xl;
  int splitStart;
};

__global__ __launch_bounds__(256)
void convert_all(CJobs J) {
  const int b = blockIdx.x;
  const int tid = threadIdx.x;
  if (b >= J.splitStart) {
    int di = (b - J.splitStart) * 256 + tid;
    int base = di * 8;
    int row = base / INP_C;
    int col0 = base - row * INP_C;
    const float* src = J.x + (size_t)row * IN_C + col0;
    float v[8];
#pragma unroll
    for (int j = 0; j < 8; ++j) v[j] = (col0 + j < IN_C) ? src[j] : 0.f;
    half8 h, l;
#pragma unroll
    for (int j = 0; j < 8; ++j) {
      _Float16 hh = (_Float16)v[j];
      h[j] = hh;
      l[j] = (_Float16)((v[j] - (float)hh) * LO_SCALE);
    }
    *(half8*)(J.xh + base) = h;
    *(half8*)(J.xl + base) = l;
    return;
  }
  int ji = 0;
#pragma unroll
  for (int i = 1; i < 6; ++i)
    if (b >= J.j[i].start) ji = i;
  const TJob job = J.j[ji];
  const int t = b - job.start;
  const int kk0 = (t % job.tK) * 32;
  const int nn0 = (t / job.tK) * 32;

  __shared__ float ts[32][33];
  const int tx = tid & 31, ty = tid >> 5;
#pragma unroll
  for (int r = 0; r < 4; ++r) {
    int kk = kk0 + ty + r * 8;
    int nn = nn0 + tx;
    ts[ty + r * 8][tx] =
        (kk < job.K && nn < job.N) ? job.src[(size_t)kk * job.N + nn] : 0.f;
  }
  __syncthreads();
  const int tw = tid & 7, rw = tid >> 3;
  const int nn = nn0 + rw, kk = kk0 + tw * 4;
  half4_t h, l;
#pragma unroll
  for (int i2 = 0; i2 < 4; ++i2) {
    float v = ts[tw * 4 + i2][rw];
    _Float16 hh = (_Float16)v;
    h[i2] = hh;
    l[i2] = (_Float16)((v - (float)hh) * LO_SCALE);
  }
  size_t o = (size_t)nn * job.Kpad + kk;
  *(half4_t*)(job.th + o) = h;
  *(half4_t*)(job.tl + o) = l;
}

// ---- layer-1: sum split-K partials + bias -> Y, per-rowband col stats ----
// grid (16, 32) = 512 blocks; block = 16 colgroups(x4 cols) x 16 rowlanes
// NOTE: Y aliases Cp[2*stride] (workspace fold) -- no __restrict__ on these;
// per-element read-then-write with data dependence, single owning thread.
__global__ __launch_bounds__(256)
void reduce_bias_stats_v(const float* Cp, const float* __restrict__ bias,
                         float* Y, float* __restrict__ psum,
                         float* __restrict__ psq, int S, size_t stride,
                         int rowsPer) {
  const int N = 1024;
  const int t = threadIdx.x;
  const int cg = t & 15, rl = t >> 4;
  const int col4 = blockIdx.x * 64 + cg * 4;
  const int r0 = blockIdx.y * rowsPer;
  const floatx4 bs = *(const floatx4*)(bias + col4);
  floatx4 s = {0.f, 0.f, 0.f, 0.f}, qq = {0.f, 0.f, 0.f, 0.f};
  for (int r = r0 + rl; r < r0 + rowsPer; r += 16) {
    size_t i = (size_t)r * N + col4;
    floatx4 v = bs;
    for (int k = 0; k < S; ++k) v += *(const floatx4*)(Cp + k * stride + i);
    *(floatx4*)(Y + i) = v;
    s += v;
    qq += v * v;
  }
  __shared__ floatx4 ls[16][16], lq[16][16];
  ls[rl][cg] = s;
  lq[rl][cg] = qq;
  __syncthreads();
  if (t < 16) {
    floatx4 S4 = {0.f, 0.f, 0.f, 0.f}, Q4 = {0.f, 0.f, 0.f, 0.f};
#pragma unroll
    for (int r = 0; r < 16; ++r) {
      S4 += ls[r][t];
      Q4 += lq[r][t];
    }
    size_t o = (size_t)blockIdx.y * N + blockIdx.x * 64 + t * 4;
    *(floatx4*)(psum + o) = S4;
    *(floatx4*)(psq + o) = Q4;
  }
}

// ---- BN finalize+apply (+res, relu) + f16 hi/lo split; float4/half4 ----
__global__ __launch_bounds__(256)
void bn_apply_v(const float* __restrict__ Y, const float* __restrict__ psum,
                const float* __restrict__ psq, const float* __restrict__ g,
                const float* __restrict__ be, const float* __restrict__ res,
                float* __restrict__ outf, _Float16* __restrict__ oh,
                _Float16* __restrict__ ol, int RB, float invM) {
  const int N = 1024;
  const int t = threadIdx.x;
  const int cg = t & 63, rl = t >> 6;
  const int col4 = blockIdx.x * 256 + cg * 4;
  __shared__ floatx4 lA[64], lB[64];
  if (t < 64) {
    int c4 = blockIdx.x * 256 + t * 4;
    floatx4 s = {0.f, 0.f, 0.f, 0.f}, qq = {0.f, 0.f, 0.f, 0.f};
    for (int rb = 0; rb < RB; ++rb) {
      s += *(const floatx4*)(psum + (size_t)rb * N + c4);
      qq += *(const floatx4*)(psq + (size_t)rb * N + c4);
    }
    floatx4 m = s * invM;
    floatx4 var = qq * invM - m * m;
    floatx4 rstd;
#pragma unroll
    for (int i = 0; i < 4; ++i) rstd[i] = rsqrtf(var[i] + 1e-5f);
    floatx4 a = (*(const floatx4*)(g + c4)) * rstd;
    lA[t] = a;
    lB[t] = (*(const floatx4*)(be + c4)) - m * a;
  }
  __syncthreads();
  const floatx4 a = lA[cg], b2 = lB[cg];
#pragma unroll
  for (int rr = 0; rr < 2; ++rr) {
    const int r = blockIdx.y * 8 + rl + rr * 4;
    const size_t i = (size_t)r * N + col4;
    floatx4 v = (*(const floatx4*)(Y + i)) * a + b2;
    if (res) v += *(const floatx4*)(res + i);
#pragma unroll
    for (int ii = 0; ii < 4; ++ii) v[ii] = fmaxf(v[ii], 0.f);
    if (outf) *(floatx4*)(outf + i) = v;
    half4_t h, l;
#pragma unroll
    for (int ii = 0; ii < 4; ++ii) {
      _Float16 hh = (_Float16)v[ii];
      h[ii] = hh;
      l[ii] = (_Float16)((v[ii] - (float)hh) * LO_SCALE);
    }
    *(half4_t*)(oh + i) = h;
    *(half4_t*)(ol + i) = l;
  }
}

// ---- polar projection (== U@Vh from SVD) * sign(det), fused with head
//      split-K reduce + bias and the betas/camera tail copy ----
__device__ __forceinline__ void cofactor3(const float X[9], float C[9]) {
  C[0] = X[4] * X[8] - X[5] * X[7];
  C[1] = X[5] * X[6] - X[3] * X[8];
  C[2] = X[3] * X[7] - X[4] * X[6];
  C[3] = X[2] * X[7] - X[1] * X[8];
  C[4] = X[0] * X[8] - X[2] * X[6];
  C[5] = X[1] * X[6] - X[0] * X[7];
  C[6] = X[1] * X[5] - X[2] * X[4];
  C[7] = X[2] * X[3] - X[0] * X[5];
  C[8] = X[0] * X[4] - X[1] * X[3];
}

__global__ __launch_bounds__(256)
void polar_tail(const float* __restrict__ Cp, const float* __restrict__ bias,
                float* __restrict__ out, int Bt, int nmat, int S,
                size_t stride) {
  const int ldy = 256;
  int idx = blockIdx.x * blockDim.x + threadIdx.x;
  if (idx < nmat) {
    int s = idx / 24, j = idx % 24;
    const size_t base = (size_t)s * ldy + j * 9;
    float A[9], X[9];
#pragma unroll
    for (int k = 0; k < 9; ++k) {
      float v = bias[j * 9 + k];
      for (int z = 0; z < S; ++z) v += Cp[z * stride + base + k];
      A[k] = v;
      X[k] = v;
    }
    double detA = (double)A[0] * ((double)A[4] * A[8] - (double)A[5] * A[7]) -
                  (double)A[1] * ((double)A[3] * A[8] - (double)A[5] * A[6]) +
                  (double)A[2] * ((double)A[3] * A[7] - (double)A[4] * A[6]);
    float sgn = (detA < 0.0) ? -1.f : 1.f;
#pragma unroll 1
    for (int it = 0; it < 12; ++it) {
      float C[9];
      cofactor3(X, C);
      float det = X[0] * C[0] + X[1] * C[1] + X[2] * C[2];
      float ad = fmaxf(fabsf(det), 1e-30f);
      float idet = (det < 0.f ? -1.f : 1.f) / ad;
      float n1 = 0.f, n2 = 0.f;
#pragma unroll
      for (int k = 0; k < 9; ++k) {
        n1 += X[k] * X[k];
        n2 += C[k] * C[k];
      }
      n1 = fmaxf(n1, 1e-30f);
      float zeta = sqrtf(sqrtf(n2 * idet * idet / n1));
      zeta = fminf(fmaxf(zeta, 1e-4f), 1e4f);
      float iz = 0.5f / zeta;
      float hz = 0.5f * zeta;
#pragma unroll
      for (int k = 0; k < 9; ++k) X[k] = hz * X[k] + iz * idet * C[k];
    }
    float* o = out + (size_t)idx * 9;
#pragma unroll
    for (int k = 0; k < 9; ++k) o[k] = X[k] * sgn;
  } else {
    int i = idx - nmat;
    int nb = Bt * 10;
    int nc = Bt * 3;
    int s, k, c;
    if (i < nb) {
      s = i / 10;
      k = i;
      c = 216 + (i % 10);
    } else if (i < nb + nc) {
      int t2 = i - nb;
      s = t2 / 3;
      k = i;
      c = 226 + (t2 % 3);
    } else {
      return;
    }
    float v = bias[c];
    size_t base = (size_t)s * ldy + c;
    for (int z = 0; z < S; ++z) v += Cp[z * stride + base];
    out[(size_t)Bt * 216 + k] = v;
  }
}

// ---------------------------------------------------------------------------
extern "C" void kernel_launch(void* const* d_in, const int* in_sizes, int n_in,
                              void* d_out, int out_size, void* d_ws,
                              size_t ws_size, hipStream_t stream) {
  const float* x = (const float*)d_in[0];
  const float* w1 = (const float*)d_in[1];
  const float* b1 = (const float*)d_in[2];
  const float* g1 = (const float*)d_in[3];
  const float* be1 = (const float*)d_in[4];
  const float* w2a = (const float*)d_in[5];
  const float* b2a = (const float*)d_in[6];
  const float* g2a = (const float*)d_in[7];
  const float* be2a = (const float*)d_in[8];
  const float* w2b = (const float*)d_in[9];
  const float* b2b = (const float*)d_in[10];
  const float* g2b = (const float*)d_in[11];
  const float* be2b = (const float*)d_in[12];
  const float* w3a = (const float*)d_in[13];
  const float* b3a = (const float*)d_in[14];
  const float* g3a = (const float*)d_in[15];
  const float* be3a = (const float*)d_in[16];
  const float* w3b = (const float*)d_in[17];
  const float* b3b = (const float*)d_in[18];
  const float* g3b = (const float*)d_in[19];
  const float* be3b = (const float*)d_in[20];
  const float* w4 = (const float*)d_in[21];
  const float* b4 = (const float*)d_in[22];
  float* out = (float*)d_out;

  const int B = 4096, IN = 10338, INP = 10368, H = 1024;
  const int OUTN = 229, OUTP = 256;
  const int RB = 32;
  const int S_L1 = 4, S_HEAD = 8;

  char* p = (char*)d_ws;
  auto alloc = [&](size_t bytes) -> void* {
    void* r = (void*)p;
    p += (bytes + 255) & ~(size_t)255;
    return r;
  };
  // 4 layer-1 split-K partials (67 MB). Splits 2/3 double as Y and Hf after
  // the reduce consumes them (element-wise read-then-write is safe); the head
  // GEMM's 8 partials (33.5 MB) fit in the splits-0/1 region. Net workspace
  // footprint unchanged vs R7.
  float* Cpart = (float*)alloc((size_t)S_L1 * B * H * 4);
  float* Y = Cpart + 2 * (size_t)B * H;
  float* Hf = Cpart + 3 * (size_t)B * H;
  _Float16* xh = (_Float16*)alloc((size_t)B * INP * 2);
  _Float16* xl = (_Float16*)alloc((size_t)B * INP * 2);
  _Float16* w1h = (_Float16*)alloc((size_t)H * INP * 2);
  _Float16* w1l = (_Float16*)alloc((size_t)H * INP * 2);
  _Float16 *wmh[4], *wml[4];
  for (int i = 0; i < 4; ++i) {
    wmh[i] = (_Float16*)alloc((size_t)H * H * 2);
    wml[i] = (_Float16*)alloc((size_t)H * H * 2);
  }
  _Float16* w4h = (_Float16*)alloc((size_t)OUTP * H * 2);
  _Float16* w4l = (_Float16*)alloc((size_t)OUTP * H * 2);
  _Float16* hh = (_Float16*)alloc((size_t)B * H * 2);
  _Float16* hl = (_Float16*)alloc((size_t)B * H * 2);
  float* psum = (float*)alloc((size_t)RB * H * 4);
  float* psq = (float*)alloc((size_t)RB * H * 4);

  // ---- conversions (one kernel) ----
  {
    CJobs J;
    const float* wsrc[6] = {w1, w2a, w2b, w3a, w3b, w4};
    _Float16* th[6] = {w1h, wmh[0], wmh[1], wmh[2], wmh[3], w4h};
    _Float16* tl[6] = {w1l, wml[0], wml[1], wml[2], wml[3], w4l};
    int Ks[6] = {IN, H, H, H, H, H};
    int Ns[6] = {H, H, H, H, H, OUTN};
    int Kpads[6] = {INP, H, H, H, H, H};
    int Npads[6] = {H, H, H, H, H, OUTP};
    int start = 0;
    for (int i = 0; i < 6; ++i) {
      J.j[i].src = wsrc[i];
      J.j[i].th = th[i];
      J.j[i].tl = tl[i];
      J.j[i].K = Ks[i];
      J.j[i].N = Ns[i];
      J.j[i].Kpad = Kpads[i];
      J.j[i].tK = Kpads[i] / 32;
      J.j[i].start = start;
      start += (Kpads[i] / 32) * (Npads[i] / 32);
    }
    J.x = x;
    J.xh = xh;
    J.xl = xl;
    J.splitStart = start;
    int total = start + (B * INP / 8 + 255) / 256;
    convert_all<<<dim3(total), 256, 0, stream>>>(J);
  }

  auto bnapply = [&](const float* g, const float* be, const float* res,
                     float* outf) {
    bn_apply_v<<<dim3(H / 256, B / 8), 256, 0, stream>>>(
        Y, psum, psq, g, be, res, outf, hh, hl, RB, 1.f / B);
  };
  // mid GEMM: S=1, bias+stats fused in epilogue, writes Y directly
  auto midgemm = [&](const _Float16* Bh, const _Float16* Bl,
                     const float* bias) {
    gemm_sk<1, true><<<dim3(B / 128, H / 128, 1), 256, 0, stream>>>(
        hh, hl, Bh, Bl, Y, H, H, H, 0, bias, psum, psq);
  };

  // layer 1 (big): 256^2 counted-vmcnt kernel, split-K=4 (grid = 256 blocks
  // = exactly 1 block/CU), then reduce
  gemm_l1<<<dim3(B / 256, H / 256, S_L1), 512, 0, stream>>>(
      xh, xl, w1h, w1l, Cpart, INP, H, INP / S_L1, (size_t)B * H);
  reduce_bias_stats_v<<<dim3(16, RB), 256, 0, stream>>>(
      Cpart, b1, Y, psum, psq, S_L1, (size_t)B * H, B / RB);
  bnapply(g1, be1, nullptr, Hf);
  // resblock 2
  midgemm(wmh[0], wml[0], b2a);
  bnapply(g2a, be2a, nullptr, nullptr);
  midgemm(wmh[1], wml[1], b2b);
  bnapply(g2b, be2b, Hf, Hf);
  // resblock 3
  midgemm(wmh[2], wml[2], b3a);
  bnapply(g3a, be3a, nullptr, nullptr);
  midgemm(wmh[3], wml[3], b3b);
  bnapply(g3b, be3b, Hf, Hf);
  // head: split-K=8, reduce fused into polar_tail
  gemm_sk<2, false><<<dim3(B / 128, OUTP / 128, S_HEAD), 256, 0, stream>>>(
      hh, hl, w4h, w4l, Cpart, H, OUTP, H / S_HEAD, (size_t)B * OUTP, nullptr,
      nullptr, nullptr);

  int nmat = B * 24;
  int ntot = nmat + B * 13;
  polar_tail<<<dim3((ntot + 255) / 256), 256, 0, stream>>>(
      Cpart, b4, out, B, nmat, S_HEAD, (size_t)B * OUTP);
}

// Round 2
// 984.543 us; speedup vs baseline: 2.0270x; 2.0270x over previous
//
#include <hip/hip_runtime.h>
#include <math.h>

// ---------------------------------------------------------------------------
// B=4096, IN=10338 (pad 10368), H=1024, OUT=229 (pad 256)
// R9: layer-1 GEMM = 128x256/BK32, 8 waves (2Mx4N), per-wave 64x64 output.
//     Counted-vmcnt schedule (T3/T4): raw s_barrier + vmcnt(6); loads stay in
//     flight across the MFMA region; setprio(1) around MFMA clusters (T5).
//     R8 post-mortem: 256x256 needed 256 acc regs -> accumulator SPILL
//     (3 GB scratch writes/dispatch, MfmaUtil 8%). This shape needs 128 acc
//     regs + ~90 others < 256 unified budget at 2 waves/SIMD -> no spill.
//     Mids/head keep the R7 gemm_sk (128^2, S=1 fused stats) unchanged.
// ---------------------------------------------------------------------------

typedef _Float16 half8 __attribute__((ext_vector_type(8)));
typedef _Float16 half4_t __attribute__((ext_vector_type(4)));
typedef float floatx4 __attribute__((ext_vector_type(4)));

#define LO_SCALE 4096.0f
#define LO_INV (1.0f / 4096.0f)
#define IN_C 10338
#define INP_C 10368

__device__ __forceinline__ void gld16(const _Float16* g, _Float16* l) {
  __builtin_amdgcn_global_load_lds(
      (const __attribute__((address_space(1))) void*)g,
      (__attribute__((address_space(3))) void*)l, 16, 0, 0);
}

// ---------------------------------------------------------------------------
// Layer-1 GEMM: 128x256 tile, BK=32, 512 threads (8 waves, 2M x 4N).
// f16 hi/lo split (lo prescaled by 4096). Per tile:
//   lgkmcnt(0); barrier; issue 6 gld16 (t+1); vmcnt(6); barrier;
//   {ds_read B-pairs + A-pairs; 48 MFMA in 2 setprio clusters}.
// Steady state never drains vmcnt; only the final tile does.
// ---------------------------------------------------------------------------
__global__ __launch_bounds__(512, 2)
void gemm_l1(const _Float16* __restrict__ Ah, const _Float16* __restrict__ Al,
             const _Float16* __restrict__ Bh, const _Float16* __restrict__ Bl,
             float* __restrict__ Cp, int Kld, int Ncols, int Ks,
             size_t partStride) {
  __shared__ _Float16 sAh[2][4096], sAl[2][4096];   // [128][32]
  __shared__ _Float16 sBh[2][8192], sBl[2][8192];   // [256][32]
  const int tid = threadIdx.x;
  const int wv = tid >> 6, ln = tid & 63;
  const int ln15 = ln & 15, q = ln >> 4;
  const int wr = wv >> 2, wc = wv & 3;  // 2M x 4N waves, 64x64 out each
  // XCD k owns M-panels {4k..4k+3} (A-panel L2 locality); grid.x=32
  const int xm = (blockIdx.x & 7) * 4 + (blockIdx.x >> 3);
  const int bm0 = xm * 128, bn0 = blockIdx.y * 256;
  const int k0 = blockIdx.z * Ks;
  Cp += (size_t)blockIdx.z * partStride;

  // staging: 512 threads cover one [128][32] array per gld16 issue.
  // source-permuted so the fixed lane->LDS placement yields the XOR-swizzle.
  const int srow = tid >> 2;                 // 0..127 (row within tile)
  const int sw = tid & 3;                    // word within row
  const int swzw = sw ^ (srow & 3) ^ ((srow >> 2) & 3);
  const size_t offA = (size_t)(bm0 + srow) * Kld + k0 + swzw * 8;
  const size_t offB0 = (size_t)(bn0 + srow) * Kld + k0 + swzw * 8;
  const size_t offB1 = (size_t)(bn0 + 128 + srow) * Kld + k0 + swzw * 8;

  // fragment reads: de-swizzle (key depends on row&15 = ln15 only)
  const int swzr = (q ^ (ln15 & 3) ^ ((ln15 >> 2) & 3)) * 8;

  floatx4 acc[4][4], acc2[4][4];
#pragma unroll
  for (int i = 0; i < 4; ++i)
#pragma unroll
    for (int j = 0; j < 4; ++j) {
      acc[i][j] = (floatx4){0.f, 0.f, 0.f, 0.f};
      acc2[i][j] = (floatx4){0.f, 0.f, 0.f, 0.f};
    }

  auto stage = [&](int kt, int buf) {
    gld16(Ah + offA + kt, &sAh[buf][wv * 512]);
    gld16(Al + offA + kt, &sAl[buf][wv * 512]);
    gld16(Bh + offB0 + kt, &sBh[buf][wv * 512]);
    gld16(Bh + offB1 + kt, &sBh[buf][4096 + wv * 512]);
    gld16(Bl + offB0 + kt, &sBl[buf][wv * 512]);
    gld16(Bl + offB1 + kt, &sBl[buf][4096 + wv * 512]);
  };

  stage(0, 0);
  int cur = 0;
  for (int kt = 0; kt < Ks; kt += 32) {
    // barrier A: own LDS reads retired; all waves done with buf[cur^1]
    asm volatile("s_waitcnt lgkmcnt(0)" ::: "memory");
    __builtin_amdgcn_s_barrier();
    __builtin_amdgcn_sched_barrier(0);
    if (kt + 32 < Ks) {
      stage(kt + 32, cur ^ 1);  // 6 loads stay in flight across this tile
      asm volatile("s_waitcnt vmcnt(6)" ::: "memory");  // tile t landed (own)
    } else {
      asm volatile("s_waitcnt vmcnt(0)" ::: "memory");  // epilogue drain
    }
    __builtin_amdgcn_s_barrier();  // barrier B: everyone's tile-t data landed
    __builtin_amdgcn_sched_barrier(0);

    const _Float16* pAh = &sAh[cur][0];
    const _Float16* pAl = &sAl[cur][0];
    const _Float16* pBh = &sBh[cur][0];
    const _Float16* pBl = &sBl[cur][0];
    half8 bhf[4], blf[4];
#pragma unroll
    for (int ni = 0; ni < 4; ++ni) {
      const int bo = (wc * 64 + ni * 16 + ln15) * 32 + swzr;
      bhf[ni] = *(const half8*)(pBh + bo);
      blf[ni] = *(const half8*)(pBl + bo);
    }
#pragma unroll
    for (int mp = 0; mp < 2; ++mp) {
      half8 ahf[2], alf[2];
#pragma unroll
      for (int i = 0; i < 2; ++i) {
        const int ao = (wr * 64 + (mp * 2 + i) * 16 + ln15) * 32 + swzr;
        ahf[i] = *(const half8*)(pAh + ao);
        alf[i] = *(const half8*)(pAl + ao);
      }
      __builtin_amdgcn_s_setprio(1);
#pragma unroll
      for (int i = 0; i < 2; ++i) {
        const int mi = mp * 2 + i;
#pragma unroll
        for (int ni = 0; ni < 4; ++ni) {
          acc[mi][ni] = __builtin_amdgcn_mfma_f32_16x16x32_f16(
              ahf[i], bhf[ni], acc[mi][ni], 0, 0, 0);
          acc2[mi][ni] = __builtin_amdgcn_mfma_f32_16x16x32_f16(
              ahf[i], blf[ni], acc2[mi][ni], 0, 0, 0);
        }
      }
      // dependent second acc2 write sits >=8 MFMAs after the first
#pragma unroll
      for (int i = 0; i < 2; ++i) {
        const int mi = mp * 2 + i;
#pragma unroll
        for (int ni = 0; ni < 4; ++ni)
          acc2[mi][ni] = __builtin_amdgcn_mfma_f32_16x16x32_f16(
              alf[i], bhf[ni], acc2[mi][ni], 0, 0, 0);
      }
      __builtin_amdgcn_s_setprio(0);
    }
    cur ^= 1;
  }

  // C/D layout: col = lane&15, row = (lane>>4)*4 + reg  [m89-verified]
#pragma unroll
  for (int mi = 0; mi < 4; ++mi)
#pragma unroll
    for (int ni = 0; ni < 4; ++ni) {
      const int col = bn0 + wc * 64 + ni * 16 + ln15;
      const int rbase = bm0 + wr * 64 + mi * 16 + q * 4;
#pragma unroll
      for (int r = 0; r < 4; ++r)
        Cp[(size_t)(rbase + r) * Ncols + col] =
            acc[mi][ni][r] + acc2[mi][ni][r] * LO_INV;
    }
}

// C_partial[z] = A[M x Ks] * BT[N x Ks]^T  (f16 hi/lo, lo prescaled by 4096)
// 128^2 tile, 4 waves. Kept for mids (S=1 fused bias+stats) and head.
template <int TAG, bool STATS>
__global__ __launch_bounds__(256, 2)
void gemm_sk(const _Float16* __restrict__ Ah, const _Float16* __restrict__ Al,
             const _Float16* __restrict__ Bh, const _Float16* __restrict__ Bl,
             float* __restrict__ Cp, int Kld, int Ncols, int Ks,
             size_t partStride, const float* __restrict__ bias,
             float* __restrict__ psum, float* __restrict__ psq) {
  __shared__ _Float16 sAh[2][4096], sAl[2][4096];
  __shared__ _Float16 sBh[2][4096], sBl[2][4096];
  const int tid = threadIdx.x;
  const int wv = tid >> 6, ln = tid & 63;
  const int ln15 = ln & 15, q = ln >> 4;
  const int wr = wv >> 1, wc = wv & 1;
  const int bm0 = blockIdx.x * 128, bn0 = blockIdx.y * 128;
  const int k0 = blockIdx.z * Ks;
  Cp += (size_t)blockIdx.z * partStride;

  const int srow = ln >> 2;
  const int swzw = (ln & 3) ^ (srow & 3) ^ ((srow >> 2) & 3);
  const int ch0 = wv * 2, ch1 = wv * 2 + 1;
  const size_t offA0 = (size_t)(bm0 + ch0 * 16 + srow) * Kld + k0 + swzw * 8;
  const size_t offA1 = (size_t)(bm0 + ch1 * 16 + srow) * Kld + k0 + swzw * 8;
  const size_t offB0 = (size_t)(bn0 + ch0 * 16 + srow) * Kld + k0 + swzw * 8;
  const size_t offB1 = (size_t)(bn0 + ch1 * 16 + srow) * Kld + k0 + swzw * 8;

  const int swzr = (q ^ (ln15 & 3) ^ ((ln15 >> 2) & 3)) * 8;
  const int aoff = (wr * 64 + ln15) * 32 + swzr;
  const int boff = (wc * 64 + ln15) * 32 + swzr;

  floatx4 acc[4][4];
  floatx4 acc2[4][4];
#pragma unroll
  for (int i = 0; i < 4; ++i)
#pragma unroll
    for (int j = 0; j < 4; ++j) {
      acc[i][j] = (floatx4){0.f, 0.f, 0.f, 0.f};
      acc2[i][j] = (floatx4){0.f, 0.f, 0.f, 0.f};
    }

  auto stage = [&](int kt, int buf) {
    gld16(Ah + offA0 + kt, &sAh[buf][ch0 * 512]);
    gld16(Ah + offA1 + kt, &sAh[buf][ch1 * 512]);
    gld16(Al + offA0 + kt, &sAl[buf][ch0 * 512]);
    gld16(Al + offA1 + kt, &sAl[buf][ch1 * 512]);
    gld16(Bh + offB0 + kt, &sBh[buf][ch0 * 512]);
    gld16(Bh + offB1 + kt, &sBh[buf][ch1 * 512]);
    gld16(Bl + offB0 + kt, &sBl[buf][ch0 * 512]);
    gld16(Bl + offB1 + kt, &sBl[buf][ch1 * 512]);
  };

  stage(0, 0);
  int cur = 0;
  for (int kt = 0; kt < Ks; kt += 32) {
    __syncthreads();
    if (kt + 32 < Ks) stage(kt + 32, cur ^ 1);

    const _Float16* pAh = &sAh[cur][aoff];
    const _Float16* pAl = &sAl[cur][aoff];
    const _Float16* pBh = &sBh[cur][boff];
    const _Float16* pBl = &sBl[cur][boff];
    half8 bh[4], bl[4];
#pragma unroll
    for (int ni = 0; ni < 4; ++ni) {
      bh[ni] = *(const half8*)(pBh + ni * 512);
      bl[ni] = *(const half8*)(pBl + ni * 512);
    }
#pragma unroll
    for (int mh = 0; mh < 2; ++mh) {
      half8 ah[2], al[2];
#pragma unroll
      for (int i = 0; i < 2; ++i) {
        ah[i] = *(const half8*)(pAh + (mh * 2 + i) * 512);
        al[i] = *(const half8*)(pAl + (mh * 2 + i) * 512);
      }
#pragma unroll
      for (int i = 0; i < 2; ++i) {
        const int mi = mh * 2 + i;
#pragma unroll
        for (int ni = 0; ni < 4; ++ni) {
          acc[mi][ni] = __builtin_amdgcn_mfma_f32_16x16x32_f16(
              ah[i], bh[ni], acc[mi][ni], 0, 0, 0);
          acc2[mi][ni] = __builtin_amdgcn_mfma_f32_16x16x32_f16(
              ah[i], bl[ni], acc2[mi][ni], 0, 0, 0);
          acc2[mi][ni] = __builtin_amdgcn_mfma_f32_16x16x32_f16(
              al[i], bh[ni], acc2[mi][ni], 0, 0, 0);
        }
      }
    }
    cur ^= 1;
  }

  // C/D layout: col = lane&15, row = (lane>>4)*4 + reg  [m89-verified]
  float bs[4];
  float sacc[4] = {0.f, 0.f, 0.f, 0.f};
  float qacc[4] = {0.f, 0.f, 0.f, 0.f};
  if constexpr (STATS) {
#pragma unroll
    for (int ni = 0; ni < 4; ++ni)
      bs[ni] = bias[bn0 + wc * 64 + ni * 16 + ln15];
  }
#pragma unroll
  for (int mi = 0; mi < 4; ++mi)
#pragma unroll
    for (int ni = 0; ni < 4; ++ni) {
      const int col = bn0 + wc * 64 + ni * 16 + ln15;
      const int rbase = bm0 + wr * 64 + mi * 16 + q * 4;
#pragma unroll
      for (int r = 0; r < 4; ++r) {
        float v = acc[mi][ni][r] + acc2[mi][ni][r] * LO_INV;
        if constexpr (STATS) {
          v += bs[ni];
          sacc[ni] += v;
          qacc[ni] += v * v;
        }
        Cp[(size_t)(rbase + r) * Ncols + col] = v;
      }
    }
  if constexpr (STATS) {
    // reuse staging LDS as scratch: 8 contributors x 128 cols
    __syncthreads();  // all waves done reading staging LDS
    float* sS = (float*)&sAh[0][0];
    float* sQ = (float*)&sAl[0][0];
    const int contrib = wr * 4 + q;  // 0..7
#pragma unroll
    for (int ni = 0; ni < 4; ++ni) {
      const int colt = wc * 64 + ni * 16 + ln15;
      sS[contrib * 128 + colt] = sacc[ni];
      sQ[contrib * 128 + colt] = qacc[ni];
    }
    __syncthreads();
    if (tid < 128) {
      float S = 0.f, Q = 0.f;
#pragma unroll
      for (int c = 0; c < 8; ++c) {
        S += sS[c * 128 + tid];
        Q += sQ[c * 128 + tid];
      }
      psum[(size_t)blockIdx.x * 1024 + bn0 + tid] = S;
      psq[(size_t)blockIdx.x * 1024 + bn0 + tid] = Q;
    }
  }
}

// ---- all conversions in one kernel ----
struct TJob {
  const float* src;
  _Float16* th;
  _Float16* tl;
  int K, N, Kpad, tK, start;
};
struct CJobs {
  TJob j[6];
  const float* x;
  _Float16* xh;
  _Float16* xl;
  int splitStart;
};

__global__ __launch_bounds__(256)
void convert_all(CJobs J) {
  const int b = blockIdx.x;
  const int tid = threadIdx.x;
  if (b >= J.splitStart) {
    int di = (b - J.splitStart) * 256 + tid;
    int base = di * 8;
    int row = base / INP_C;
    int col0 = base - row * INP_C;
    const float* src = J.x + (size_t)row * IN_C + col0;
    float v[8];
#pragma unroll
    for (int j = 0; j < 8; ++j) v[j] = (col0 + j < IN_C) ? src[j] : 0.f;
    half8 h, l;
#pragma unroll
    for (int j = 0; j < 8; ++j) {
      _Float16 hh = (_Float16)v[j];
      h[j] = hh;
      l[j] = (_Float16)((v[j] - (float)hh) * LO_SCALE);
    }
    *(half8*)(J.xh + base) = h;
    *(half8*)(J.xl + base) = l;
    return;
  }
  int ji = 0;
#pragma unroll
  for (int i = 1; i < 6; ++i)
    if (b >= J.j[i].start) ji = i;
  const TJob job = J.j[ji];
  const int t = b - job.start;
  const int kk0 = (t % job.tK) * 32;
  const int nn0 = (t / job.tK) * 32;

  __shared__ float ts[32][33];
  const int tx = tid & 31, ty = tid >> 5;
#pragma unroll
  for (int r = 0; r < 4; ++r) {
    int kk = kk0 + ty + r * 8;
    int nn = nn0 + tx;
    ts[ty + r * 8][tx] =
        (kk < job.K && nn < job.N) ? job.src[(size_t)kk * job.N + nn] : 0.f;
  }
  __syncthreads();
  const int tw = tid & 7, rw = tid >> 3;
  const int nn = nn0 + rw, kk = kk0 + tw * 4;
  half4_t h, l;
#pragma unroll
  for (int i2 = 0; i2 < 4; ++i2) {
    float v = ts[tw * 4 + i2][rw];
    _Float16 hh = (_Float16)v;
    h[i2] = hh;
    l[i2] = (_Float16)((v - (float)hh) * LO_SCALE);
  }
  size_t o = (size_t)nn * job.Kpad + kk;
  *(half4_t*)(job.th + o) = h;
  *(half4_t*)(job.tl + o) = l;
}

// ---- layer-1: sum split-K partials + bias -> Y, per-rowband col stats ----
// grid (16, 32) = 512 blocks; block = 16 colgroups(x4 cols) x 16 rowlanes
// NOTE: Y lives in the Cpart arena (workspace fold) but with S=2 the read
// slices {0,1} and write slice {2} are disjoint.
__global__ __launch_bounds__(256)
void reduce_bias_stats_v(const float* Cp, const float* __restrict__ bias,
                         float* Y, float* __restrict__ psum,
                         float* __restrict__ psq, int S, size_t stride,
                         int rowsPer) {
  const int N = 1024;
  const int t = threadIdx.x;
  const int cg = t & 15, rl = t >> 4;
  const int col4 = blockIdx.x * 64 + cg * 4;
  const int r0 = blockIdx.y * rowsPer;
  const floatx4 bs = *(const floatx4*)(bias + col4);
  floatx4 s = {0.f, 0.f, 0.f, 0.f}, qq = {0.f, 0.f, 0.f, 0.f};
  for (int r = r0 + rl; r < r0 + rowsPer; r += 16) {
    size_t i = (size_t)r * N + col4;
    floatx4 v = bs;
    for (int k = 0; k < S; ++k) v += *(const floatx4*)(Cp + k * stride + i);
    *(floatx4*)(Y + i) = v;
    s += v;
    qq += v * v;
  }
  __shared__ floatx4 ls[16][16], lq[16][16];
  ls[rl][cg] = s;
  lq[rl][cg] = qq;
  __syncthreads();
  if (t < 16) {
    floatx4 S4 = {0.f, 0.f, 0.f, 0.f}, Q4 = {0.f, 0.f, 0.f, 0.f};
#pragma unroll
    for (int r = 0; r < 16; ++r) {
      S4 += ls[r][t];
      Q4 += lq[r][t];
    }
    size_t o = (size_t)blockIdx.y * N + blockIdx.x * 64 + t * 4;
    *(floatx4*)(psum + o) = S4;
    *(floatx4*)(psq + o) = Q4;
  }
}

// ---- BN finalize+apply (+res, relu) + f16 hi/lo split; float4/half4 ----
__global__ __launch_bounds__(256)
void bn_apply_v(const float* __restrict__ Y, const float* __restrict__ psum,
                const float* __restrict__ psq, const float* __restrict__ g,
                const float* __restrict__ be, const float* __restrict__ res,
                float* __restrict__ outf, _Float16* __restrict__ oh,
                _Float16* __restrict__ ol, int RB, float invM) {
  const int N = 1024;
  const int t = threadIdx.x;
  const int cg = t & 63, rl = t >> 6;
  const int col4 = blockIdx.x * 256 + cg * 4;
  __shared__ floatx4 lA[64], lB[64];
  if (t < 64) {
    int c4 = blockIdx.x * 256 + t * 4;
    floatx4 s = {0.f, 0.f, 0.f, 0.f}, qq = {0.f, 0.f, 0.f, 0.f};
    for (int rb = 0; rb < RB; ++rb) {
      s += *(const floatx4*)(psum + (size_t)rb * N + c4);
      qq += *(const floatx4*)(psq + (size_t)rb * N + c4);
    }
    floatx4 m = s * invM;
    floatx4 var = qq * invM - m * m;
    floatx4 rstd;
#pragma unroll
    for (int i = 0; i < 4; ++i) rstd[i] = rsqrtf(var[i] + 1e-5f);
    floatx4 a = (*(const floatx4*)(g + c4)) * rstd;
    lA[t] = a;
    lB[t] = (*(const floatx4*)(be + c4)) - m * a;
  }
  __syncthreads();
  const floatx4 a = lA[cg], b2 = lB[cg];
#pragma unroll
  for (int rr = 0; rr < 2; ++rr) {
    const int r = blockIdx.y * 8 + rl + rr * 4;
    const size_t i = (size_t)r * N + col4;
    floatx4 v = (*(const floatx4*)(Y + i)) * a + b2;
    if (res) v += *(const floatx4*)(res + i);
#pragma unroll
    for (int ii = 0; ii < 4; ++ii) v[ii] = fmaxf(v[ii], 0.f);
    if (outf) *(floatx4*)(outf + i) = v;
    half4_t h, l;
#pragma unroll
    for (int ii = 0; ii < 4; ++ii) {
      _Float16 hh = (_Float16)v[ii];
      h[ii] = hh;
      l[ii] = (_Float16)((v[ii] - (float)hh) * LO_SCALE);
    }
    *(half4_t*)(oh + i) = h;
    *(half4_t*)(ol + i) = l;
  }
}

// ---- polar projection (== U@Vh from SVD) * sign(det), fused with head
//      split-K reduce + bias and the betas/camera tail copy ----
__device__ __forceinline__ void cofactor3(const float X[9], float C[9]) {
  C[0] = X[4] * X[8] - X[5] * X[7];
  C[1] = X[5] * X[6] - X[3] * X[8];
  C[2] = X[3] * X[7] - X[4] * X[6];
  C[3] = X[2] * X[7] - X[1] * X[8];
  C[4] = X[0] * X[8] - X[2] * X[6];
  C[5] = X[1] * X[6] - X[0] * X[7];
  C[6] = X[1] * X[5] - X[2] * X[4];
  C[7] = X[2] * X[3] - X[0] * X[5];
  C[8] = X[0] * X[4] - X[1] * X[3];
}

__global__ __launch_bounds__(256)
void polar_tail(const float* __restrict__ Cp, const float* __restrict__ bias,
                float* __restrict__ out, int Bt, int nmat, int S,
                size_t stride) {
  const int ldy = 256;
  int idx = blockIdx.x * blockDim.x + threadIdx.x;
  if (idx < nmat) {
    int s = idx / 24, j = idx % 24;
    const size_t base = (size_t)s * ldy + j * 9;
    float A[9], X[9];
#pragma unroll
    for (int k = 0; k < 9; ++k) {
      float v = bias[j * 9 + k];
      for (int z = 0; z < S; ++z) v += Cp[z * stride + base + k];
      A[k] = v;
      X[k] = v;
    }
    double detA = (double)A[0] * ((double)A[4] * A[8] - (double)A[5] * A[7]) -
                  (double)A[1] * ((double)A[3] * A[8] - (double)A[5] * A[6]) +
                  (double)A[2] * ((double)A[3] * A[7] - (double)A[4] * A[6]);
    float sgn = (detA < 0.0) ? -1.f : 1.f;
#pragma unroll 1
    for (int it = 0; it < 12; ++it) {
      float C[9];
      cofactor3(X, C);
      float det = X[0] * C[0] + X[1] * C[1] + X[2] * C[2];
      float ad = fmaxf(fabsf(det), 1e-30f);
      float idet = (det < 0.f ? -1.f : 1.f) / ad;
      float n1 = 0.f, n2 = 0.f;
#pragma unroll
      for (int k = 0; k < 9; ++k) {
        n1 += X[k] * X[k];
        n2 += C[k] * C[k];
      }
      n1 = fmaxf(n1, 1e-30f);
      float zeta = sqrtf(sqrtf(n2 * idet * idet / n1));
      zeta = fminf(fmaxf(zeta, 1e-4f), 1e4f);
      float iz = 0.5f / zeta;
      float hz = 0.5f * zeta;
#pragma unroll
      for (int k = 0; k < 9; ++k) X[k] = hz * X[k] + iz * idet * C[k];
    }
    float* o = out + (size_t)idx * 9;
#pragma unroll
    for (int k = 0; k < 9; ++k) o[k] = X[k] * sgn;
  } else {
    int i = idx - nmat;
    int nb = Bt * 10;
    int nc = Bt * 3;
    int s, k, c;
    if (i < nb) {
      s = i / 10;
      k = i;
      c = 216 + (i % 10);
    } else if (i < nb + nc) {
      int t2 = i - nb;
      s = t2 / 3;
      k = i;
      c = 226 + (t2 % 3);
    } else {
      return;
    }
    float v = bias[c];
    size_t base = (size_t)s * ldy + c;
    for (int z = 0; z < S; ++z) v += Cp[z * stride + base];
    out[(size_t)Bt * 216 + k] = v;
  }
}

// ---------------------------------------------------------------------------
extern "C" void kernel_launch(void* const* d_in, const int* in_sizes, int n_in,
                              void* d_out, int out_size, void* d_ws,
                              size_t ws_size, hipStream_t stream) {
  const float* x = (const float*)d_in[0];
  const float* w1 = (const float*)d_in[1];
  const float* b1 = (const float*)d_in[2];
  const float* g1 = (const float*)d_in[3];
  const float* be1 = (const float*)d_in[4];
  const float* w2a = (const float*)d_in[5];
  const float* b2a = (const float*)d_in[6];
  const float* g2a = (const float*)d_in[7];
  const float* be2a = (const float*)d_in[8];
  const float* w2b = (const float*)d_in[9];
  const float* b2b = (const float*)d_in[10];
  const float* g2b = (const float*)d_in[11];
  const float* be2b = (const float*)d_in[12];
  const float* w3a = (const float*)d_in[13];
  const float* b3a = (const float*)d_in[14];
  const float* g3a = (const float*)d_in[15];
  const float* be3a = (const float*)d_in[16];
  const float* w3b = (const float*)d_in[17];
  const float* b3b = (const float*)d_in[18];
  const float* g3b = (const float*)d_in[19];
  const float* be3b = (const float*)d_in[20];
  const float* w4 = (const float*)d_in[21];
  const float* b4 = (const float*)d_in[22];
  float* out = (float*)d_out;

  const int B = 4096, IN = 10338, INP = 10368, H = 1024;
  const int OUTN = 229, OUTP = 256;
  const int RB = 32;
  const int S_L1 = 2, S_HEAD = 8;

  char* p = (char*)d_ws;
  auto alloc = [&](size_t bytes) -> void* {
    void* r = (void*)p;
    p += (bytes + 255) & ~(size_t)255;
    return r;
  };
  // Cpart arena: 4 x B*H slices. Layer-1 split-K=2 uses slices {0,1};
  // Y = slice 2, Hf = slice 3 (disjoint). Head's 8 x B*OUTP partials
  // (33.5 MB) fit exactly in slices {0,1}, reused after layer 1.
  float* Cpart = (float*)alloc((size_t)4 * B * H * 4);
  float* Y = Cpart + 2 * (size_t)B * H;
  float* Hf = Cpart + 3 * (size_t)B * H;
  _Float16* xh = (_Float16*)alloc((size_t)B * INP * 2);
  _Float16* xl = (_Float16*)alloc((size_t)B * INP * 2);
  _Float16* w1h = (_Float16*)alloc((size_t)H * INP * 2);
  _Float16* w1l = (_Float16*)alloc((size_t)H * INP * 2);
  _Float16 *wmh[4], *wml[4];
  for (int i = 0; i < 4; ++i) {
    wmh[i] = (_Float16*)alloc((size_t)H * H * 2);
    wml[i] = (_Float16*)alloc((size_t)H * H * 2);
  }
  _Float16* w4h = (_Float16*)alloc((size_t)OUTP * H * 2);
  _Float16* w4l = (_Float16*)alloc((size_t)OUTP * H * 2);
  _Float16* hh = (_Float16*)alloc((size_t)B * H * 2);
  _Float16* hl = (_Float16*)alloc((size_t)B * H * 2);
  float* psum = (float*)alloc((size_t)RB * H * 4);
  float* psq = (float*)alloc((size_t)RB * H * 4);

  // ---- conversions (one kernel) ----
  {
    CJobs J;
    const float* wsrc[6] = {w1, w2a, w2b, w3a, w3b, w4};
    _Float16* th[6] = {w1h, wmh[0], wmh[1], wmh[2], wmh[3], w4h};
    _Float16* tl[6] = {w1l, wml[0], wml[1], wml[2], wml[3], w4l};
    int Ks[6] = {IN, H, H, H, H, H};
    int Ns[6] = {H, H, H, H, H, OUTN};
    int Kpads[6] = {INP, H, H, H, H, H};
    int Npads[6] = {H, H, H, H, H, OUTP};
    int start = 0;
    for (int i = 0; i < 6; ++i) {
      J.j[i].src = wsrc[i];
      J.j[i].th = th[i];
      J.j[i].tl = tl[i];
      J.j[i].K = Ks[i];
      J.j[i].N = Ns[i];
      J.j[i].Kpad = Kpads[i];
      J.j[i].tK = Kpads[i] / 32;
      J.j[i].start = start;
      start += (Kpads[i] / 32) * (Npads[i] / 32);
    }
    J.x = x;
    J.xh = xh;
    J.xl = xl;
    J.splitStart = start;
    int total = start + (B * INP / 8 + 255) / 256;
    convert_all<<<dim3(total), 256, 0, stream>>>(J);
  }

  auto bnapply = [&](const float* g, const float* be, const float* res,
                     float* outf) {
    bn_apply_v<<<dim3(H / 256, B / 8), 256, 0, stream>>>(
        Y, psum, psq, g, be, res, outf, hh, hl, RB, 1.f / B);
  };
  // mid GEMM: S=1, bias+stats fused in epilogue, writes Y directly
  auto midgemm = [&](const _Float16* Bh, const _Float16* Bl,
                     const float* bias) {
    gemm_sk<1, true><<<dim3(B / 128, H / 128, 1), 256, 0, stream>>>(
        hh, hl, Bh, Bl, Y, H, H, H, 0, bias, psum, psq);
  };

  // layer 1 (big): 128x256 counted-vmcnt kernel, split-K=2
  // grid = 32 x 4 x 2 = 256 blocks = exactly 1 block/CU
  gemm_l1<<<dim3(B / 128, H / 256, S_L1), 512, 0, stream>>>(
      xh, xl, w1h, w1l, Cpart, INP, H, INP / S_L1, (size_t)B * H);
  reduce_bias_stats_v<<<dim3(16, RB), 256, 0, stream>>>(
      Cpart, b1, Y, psum, psq, S_L1, (size_t)B * H, B / RB);
  bnapply(g1, be1, nullptr, Hf);
  // resblock 2
  midgemm(wmh[0], wml[0], b2a);
  bnapply(g2a, be2a, nullptr, nullptr);
  midgemm(wmh[1], wml[1], b2b);
  bnapply(g2b, be2b, Hf, Hf);
  // resblock 3
  midgemm(wmh[2], wml[2], b3a);
  bnapply(g3a, be3a, nullptr, nullptr);
  midgemm(wmh[3], wml[3], b3b);
  bnapply(g3b, be3b, Hf, Hf);
  // head: split-K=8, reduce fused into polar_tail
  gemm_sk<2, false><<<dim3(B / 128, OUTP / 128, S_HEAD), 256, 0, stream>>>(
      hh, hl, w4h, w4l, Cpart, H, OUTP, H / S_HEAD, (size_t)B * OUTP, nullptr,
      nullptr, nullptr);

  int nmat = B * 24;
  int ntot = nmat + B * 13;
  polar_tail<<<dim3((ntot + 255) / 256), 256, 0, stream>>>(
      Cpart, b4, out, B, nmat, S_HEAD, (size_t)B * OUTP);
}

// Round 3
// 887.624 us; speedup vs baseline: 2.2483x; 1.1092x over previous
//
#include <hip/hip_runtime.h>
#include <math.h>

// ---------------------------------------------------------------------------
// B=4096, IN=10338 (pad 10368), H=1024, OUT=229 (pad 256)
// R10: layer-1 reverted to the R7-proven gemm_sk 128^2 / 2-blocks-per-CU
//      (R8/R9 post-mortem: 1-block/CU barrier-lockstep alternates LDS and
//      MFMA phases -> 33% MfmaUtil; inter-block overlap is what delivers
//      R7's 41%). Mids get the same medicine: tile 128x64 -> grid 512
//      blocks = 2 blocks/CU (was 256 = 1/CU lockstep), LDS 48KB, S=1
//      fused bias+stats epilogue kept.
// ---------------------------------------------------------------------------

typedef _Float16 half8 __attribute__((ext_vector_type(8)));
typedef _Float16 half4_t __attribute__((ext_vector_type(4)));
typedef float floatx4 __attribute__((ext_vector_type(4)));

#define LO_SCALE 4096.0f
#define LO_INV (1.0f / 4096.0f)
#define IN_C 10338
#define INP_C 10368

__device__ __forceinline__ void gld16(const _Float16* g, _Float16* l) {
  __builtin_amdgcn_global_load_lds(
      (const __attribute__((address_space(1))) void*)g,
      (__attribute__((address_space(3))) void*)l, 16, 0, 0);
}

// C_partial[z] = A[M x Ks] * BT[N x Ks]^T  (f16 hi/lo, lo prescaled by 4096)
// 128^2 tile, 4 waves, 2 blocks/CU. Used for layer 1 (split-K) and head.
template <int TAG, bool STATS>
__global__ __launch_bounds__(256, 2)
void gemm_sk(const _Float16* __restrict__ Ah, const _Float16* __restrict__ Al,
             const _Float16* __restrict__ Bh, const _Float16* __restrict__ Bl,
             float* __restrict__ Cp, int Kld, int Ncols, int Ks,
             size_t partStride, const float* __restrict__ bias,
             float* __restrict__ psum, float* __restrict__ psq) {
  __shared__ _Float16 sAh[2][4096], sAl[2][4096];
  __shared__ _Float16 sBh[2][4096], sBl[2][4096];
  const int tid = threadIdx.x;
  const int wv = tid >> 6, ln = tid & 63;
  const int ln15 = ln & 15, q = ln >> 4;
  const int wr = wv >> 1, wc = wv & 1;
  const int bm0 = blockIdx.x * 128, bn0 = blockIdx.y * 128;
  const int k0 = blockIdx.z * Ks;
  Cp += (size_t)blockIdx.z * partStride;

  const int srow = ln >> 2;
  const int swzw = (ln & 3) ^ (srow & 3) ^ ((srow >> 2) & 3);
  const int ch0 = wv * 2, ch1 = wv * 2 + 1;
  const size_t offA0 = (size_t)(bm0 + ch0 * 16 + srow) * Kld + k0 + swzw * 8;
  const size_t offA1 = (size_t)(bm0 + ch1 * 16 + srow) * Kld + k0 + swzw * 8;
  const size_t offB0 = (size_t)(bn0 + ch0 * 16 + srow) * Kld + k0 + swzw * 8;
  const size_t offB1 = (size_t)(bn0 + ch1 * 16 + srow) * Kld + k0 + swzw * 8;

  const int swzr = (q ^ (ln15 & 3) ^ ((ln15 >> 2) & 3)) * 8;
  const int aoff = (wr * 64 + ln15) * 32 + swzr;
  const int boff = (wc * 64 + ln15) * 32 + swzr;

  floatx4 acc[4][4];
  floatx4 acc2[4][4];
#pragma unroll
  for (int i = 0; i < 4; ++i)
#pragma unroll
    for (int j = 0; j < 4; ++j) {
      acc[i][j] = (floatx4){0.f, 0.f, 0.f, 0.f};
      acc2[i][j] = (floatx4){0.f, 0.f, 0.f, 0.f};
    }

  auto stage = [&](int kt, int buf) {
    gld16(Ah + offA0 + kt, &sAh[buf][ch0 * 512]);
    gld16(Ah + offA1 + kt, &sAh[buf][ch1 * 512]);
    gld16(Al + offA0 + kt, &sAl[buf][ch0 * 512]);
    gld16(Al + offA1 + kt, &sAl[buf][ch1 * 512]);
    gld16(Bh + offB0 + kt, &sBh[buf][ch0 * 512]);
    gld16(Bh + offB1 + kt, &sBh[buf][ch1 * 512]);
    gld16(Bl + offB0 + kt, &sBl[buf][ch0 * 512]);
    gld16(Bl + offB1 + kt, &sBl[buf][ch1 * 512]);
  };

  stage(0, 0);
  int cur = 0;
  for (int kt = 0; kt < Ks; kt += 32) {
    __syncthreads();
    if (kt + 32 < Ks) stage(kt + 32, cur ^ 1);

    const _Float16* pAh = &sAh[cur][aoff];
    const _Float16* pAl = &sAl[cur][aoff];
    const _Float16* pBh = &sBh[cur][boff];
    const _Float16* pBl = &sBl[cur][boff];
    half8 bh[4], bl[4];
#pragma unroll
    for (int ni = 0; ni < 4; ++ni) {
      bh[ni] = *(const half8*)(pBh + ni * 512);
      bl[ni] = *(const half8*)(pBl + ni * 512);
    }
#pragma unroll
    for (int mh = 0; mh < 2; ++mh) {
      half8 ah[2], al[2];
#pragma unroll
      for (int i = 0; i < 2; ++i) {
        ah[i] = *(const half8*)(pAh + (mh * 2 + i) * 512);
        al[i] = *(const half8*)(pAl + (mh * 2 + i) * 512);
      }
#pragma unroll
      for (int i = 0; i < 2; ++i) {
        const int mi = mh * 2 + i;
#pragma unroll
        for (int ni = 0; ni < 4; ++ni) {
          acc[mi][ni] = __builtin_amdgcn_mfma_f32_16x16x32_f16(
              ah[i], bh[ni], acc[mi][ni], 0, 0, 0);
          acc2[mi][ni] = __builtin_amdgcn_mfma_f32_16x16x32_f16(
              ah[i], bl[ni], acc2[mi][ni], 0, 0, 0);
          acc2[mi][ni] = __builtin_amdgcn_mfma_f32_16x16x32_f16(
              al[i], bh[ni], acc2[mi][ni], 0, 0, 0);
        }
      }
    }
    cur ^= 1;
  }

  // C/D layout: col = lane&15, row = (lane>>4)*4 + reg  [m89-verified]
  float bs[4];
  float sacc[4] = {0.f, 0.f, 0.f, 0.f};
  float qacc[4] = {0.f, 0.f, 0.f, 0.f};
  if constexpr (STATS) {
#pragma unroll
    for (int ni = 0; ni < 4; ++ni)
      bs[ni] = bias[bn0 + wc * 64 + ni * 16 + ln15];
  }
#pragma unroll
  for (int mi = 0; mi < 4; ++mi)
#pragma unroll
    for (int ni = 0; ni < 4; ++ni) {
      const int col = bn0 + wc * 64 + ni * 16 + ln15;
      const int rbase = bm0 + wr * 64 + mi * 16 + q * 4;
#pragma unroll
      for (int r = 0; r < 4; ++r) {
        float v = acc[mi][ni][r] + acc2[mi][ni][r] * LO_INV;
        if constexpr (STATS) {
          v += bs[ni];
          sacc[ni] += v;
          qacc[ni] += v * v;
        }
        Cp[(size_t)(rbase + r) * Ncols + col] = v;
      }
    }
  if constexpr (STATS) {
    __syncthreads();
    float* sS = (float*)&sAh[0][0];
    float* sQ = (float*)&sAl[0][0];
    const int contrib = wr * 4 + q;  // 0..7
#pragma unroll
    for (int ni = 0; ni < 4; ++ni) {
      const int colt = wc * 64 + ni * 16 + ln15;
      sS[contrib * 128 + colt] = sacc[ni];
      sQ[contrib * 128 + colt] = qacc[ni];
    }
    __syncthreads();
    if (tid < 128) {
      float S = 0.f, Q = 0.f;
#pragma unroll
      for (int c = 0; c < 8; ++c) {
        S += sS[c * 128 + tid];
        Q += sQ[c * 128 + tid];
      }
      psum[(size_t)blockIdx.x * 1024 + bn0 + tid] = S;
      psq[(size_t)blockIdx.x * 1024 + bn0 + tid] = Q;
    }
  }
}

// ---------------------------------------------------------------------------
// Mid GEMM: tile 128(M) x 64(N), BK=32, 4 waves as 2Mx2N (per-wave 64x32).
// LDS 48KB -> 2 blocks/CU at grid (32,16)=512 blocks (inter-block overlap,
// the R9 lesson). S=1: bias + per-block column stats fused in epilogue.
// ---------------------------------------------------------------------------
__global__ __launch_bounds__(256, 2)
void gemm_mid(const _Float16* __restrict__ Ah, const _Float16* __restrict__ Al,
              const _Float16* __restrict__ Bh, const _Float16* __restrict__ Bl,
              float* __restrict__ Y, int Kld, int Ncols, int Ks,
              const float* __restrict__ bias, float* __restrict__ psum,
              float* __restrict__ psq) {
  __shared__ _Float16 sAh[2][4096], sAl[2][4096];  // [128][32]
  __shared__ _Float16 sBh[2][2048], sBl[2][2048];  // [64][32]
  const int tid = threadIdx.x;
  const int wv = tid >> 6, ln = tid & 63;
  const int ln15 = ln & 15, q = ln >> 4;
  const int wr = wv >> 1, wc = wv & 1;  // 2M x 2N waves, 64x32 out each
  const int bm0 = blockIdx.x * 128, bn0 = blockIdx.y * 64;

  // staging: per-wave 16-row chunks; source-permuted XOR swizzle (row&15 key)
  const int srow = ln >> 2;
  const int swzw = (ln & 3) ^ (srow & 3) ^ ((srow >> 2) & 3);
  const int ch0 = wv * 2, ch1 = wv * 2 + 1;
  const size_t offA0 = (size_t)(bm0 + ch0 * 16 + srow) * Kld + swzw * 8;
  const size_t offA1 = (size_t)(bm0 + ch1 * 16 + srow) * Kld + swzw * 8;
  const size_t offB = (size_t)(bn0 + wv * 16 + srow) * Kld + swzw * 8;

  // fragment reads: de-swizzle
  const int swzr = (q ^ (ln15 & 3) ^ ((ln15 >> 2) & 3)) * 8;
  const int aoff = (wr * 64 + ln15) * 32 + swzr;
  const int boff = (wc * 32 + ln15) * 32 + swzr;

  floatx4 acc[4][2], acc2[4][2];
#pragma unroll
  for (int i = 0; i < 4; ++i)
#pragma unroll
    for (int j = 0; j < 2; ++j) {
      acc[i][j] = (floatx4){0.f, 0.f, 0.f, 0.f};
      acc2[i][j] = (floatx4){0.f, 0.f, 0.f, 0.f};
    }

  auto stage = [&](int kt, int buf) {
    gld16(Ah + offA0 + kt, &sAh[buf][ch0 * 512]);
    gld16(Ah + offA1 + kt, &sAh[buf][ch1 * 512]);
    gld16(Al + offA0 + kt, &sAl[buf][ch0 * 512]);
    gld16(Al + offA1 + kt, &sAl[buf][ch1 * 512]);
    gld16(Bh + offB + kt, &sBh[buf][wv * 512]);
    gld16(Bl + offB + kt, &sBl[buf][wv * 512]);
  };

  stage(0, 0);
  int cur = 0;
  for (int kt = 0; kt < Ks; kt += 32) {
    __syncthreads();
    if (kt + 32 < Ks) stage(kt + 32, cur ^ 1);

    const _Float16* pAh = &sAh[cur][aoff];
    const _Float16* pAl = &sAl[cur][aoff];
    const _Float16* pBh = &sBh[cur][boff];
    const _Float16* pBl = &sBl[cur][boff];
    half8 bh[2], bl[2];
#pragma unroll
    for (int ni = 0; ni < 2; ++ni) {
      bh[ni] = *(const half8*)(pBh + ni * 512);
      bl[ni] = *(const half8*)(pBl + ni * 512);
    }
#pragma unroll
    for (int mh = 0; mh < 2; ++mh) {
      half8 ah[2], al[2];
#pragma unroll
      for (int i = 0; i < 2; ++i) {
        ah[i] = *(const half8*)(pAh + (mh * 2 + i) * 512);
        al[i] = *(const half8*)(pAl + (mh * 2 + i) * 512);
      }
#pragma unroll
      for (int i = 0; i < 2; ++i) {
        const int mi = mh * 2 + i;
#pragma unroll
        for (int ni = 0; ni < 2; ++ni) {
          acc[mi][ni] = __builtin_amdgcn_mfma_f32_16x16x32_f16(
              ah[i], bh[ni], acc[mi][ni], 0, 0, 0);
          acc2[mi][ni] = __builtin_amdgcn_mfma_f32_16x16x32_f16(
              ah[i], bl[ni], acc2[mi][ni], 0, 0, 0);
          acc2[mi][ni] = __builtin_amdgcn_mfma_f32_16x16x32_f16(
              al[i], bh[ni], acc2[mi][ni], 0, 0, 0);
        }
      }
    }
    cur ^= 1;
  }

  // epilogue: bias + Y write + column stats (per-block partials)
  float bs[2];
  float sacc[2] = {0.f, 0.f};
  float qacc[2] = {0.f, 0.f};
#pragma unroll
  for (int ni = 0; ni < 2; ++ni)
    bs[ni] = bias[bn0 + wc * 32 + ni * 16 + ln15];
#pragma unroll
  for (int mi = 0; mi < 4; ++mi)
#pragma unroll
    for (int ni = 0; ni < 2; ++ni) {
      const int col = bn0 + wc * 32 + ni * 16 + ln15;
      const int rbase = bm0 + wr * 64 + mi * 16 + q * 4;
#pragma unroll
      for (int r = 0; r < 4; ++r) {
        float v = acc[mi][ni][r] + acc2[mi][ni][r] * LO_INV + bs[ni];
        sacc[ni] += v;
        qacc[ni] += v * v;
        Y[(size_t)(rbase + r) * Ncols + col] = v;
      }
    }
  // reuse staging LDS as scratch: 8 contributors x 64 cols
  __syncthreads();
  float* sS = (float*)&sAh[0][0];
  float* sQ = (float*)&sAl[0][0];
  const int contrib = wr * 4 + q;  // 0..7
#pragma unroll
  for (int ni = 0; ni < 2; ++ni) {
    const int colt = wc * 32 + ni * 16 + ln15;
    sS[contrib * 64 + colt] = sacc[ni];
    sQ[contrib * 64 + colt] = qacc[ni];
  }
  __syncthreads();
  if (tid < 64) {
    float S = 0.f, Q = 0.f;
#pragma unroll
    for (int c = 0; c < 8; ++c) {
      S += sS[c * 64 + tid];
      Q += sQ[c * 64 + tid];
    }
    psum[(size_t)blockIdx.x * 1024 + bn0 + tid] = S;
    psq[(size_t)blockIdx.x * 1024 + bn0 + tid] = Q;
  }
}

// ---- all conversions in one kernel ----
struct TJob {
  const float* src;
  _Float16* th;
  _Float16* tl;
  int K, N, Kpad, tK, start;
};
struct CJobs {
  TJob j[6];
  const float* x;
  _Float16* xh;
  _Float16* xl;
  int splitStart;
};

__global__ __launch_bounds__(256)
void convert_all(CJobs J) {
  const int b = blockIdx.x;
  const int tid = threadIdx.x;
  if (b >= J.splitStart) {
    int di = (b - J.splitStart) * 256 + tid;
    int base = di * 8;
    int row = base / INP_C;
    int col0 = base - row * INP_C;
    const float* src = J.x + (size_t)row * IN_C + col0;
    float v[8];
#pragma unroll
    for (int j = 0; j < 8; ++j) v[j] = (col0 + j < IN_C) ? src[j] : 0.f;
    half8 h, l;
#pragma unroll
    for (int j = 0; j < 8; ++j) {
      _Float16 hh = (_Float16)v[j];
      h[j] = hh;
      l[j] = (_Float16)((v[j] - (float)hh) * LO_SCALE);
    }
    *(half8*)(J.xh + base) = h;
    *(half8*)(J.xl + base) = l;
    return;
  }
  int ji = 0;
#pragma unroll
  for (int i = 1; i < 6; ++i)
    if (b >= J.j[i].start) ji = i;
  const TJob job = J.j[ji];
  const int t = b - job.start;
  const int kk0 = (t % job.tK) * 32;
  const int nn0 = (t / job.tK) * 32;

  __shared__ float ts[32][33];
  const int tx = tid & 31, ty = tid >> 5;
#pragma unroll
  for (int r = 0; r < 4; ++r) {
    int kk = kk0 + ty + r * 8;
    int nn = nn0 + tx;
    ts[ty + r * 8][tx] =
        (kk < job.K && nn < job.N) ? job.src[(size_t)kk * job.N + nn] : 0.f;
  }
  __syncthreads();
  const int tw = tid & 7, rw = tid >> 3;
  const int nn = nn0 + rw, kk = kk0 + tw * 4;
  half4_t h, l;
#pragma unroll
  for (int i2 = 0; i2 < 4; ++i2) {
    float v = ts[tw * 4 + i2][rw];
    _Float16 hh = (_Float16)v;
    h[i2] = hh;
    l[i2] = (_Float16)((v - (float)hh) * LO_SCALE);
  }
  size_t o = (size_t)nn * job.Kpad + kk;
  *(half4_t*)(job.th + o) = h;
  *(half4_t*)(job.tl + o) = l;
}

// ---- layer-1: sum split-K partials + bias -> Y, per-rowband col stats ----
// NOTE: Y lives in the Cpart arena (workspace fold) but with S=2 the read
// slices {0,1} and write slice {2} are disjoint.
__global__ __launch_bounds__(256)
void reduce_bias_stats_v(const float* Cp, const float* __restrict__ bias,
                         float* Y, float* __restrict__ psum,
                         float* __restrict__ psq, int S, size_t stride,
                         int rowsPer) {
  const int N = 1024;
  const int t = threadIdx.x;
  const int cg = t & 15, rl = t >> 4;
  const int col4 = blockIdx.x * 64 + cg * 4;
  const int r0 = blockIdx.y * rowsPer;
  const floatx4 bs = *(const floatx4*)(bias + col4);
  floatx4 s = {0.f, 0.f, 0.f, 0.f}, qq = {0.f, 0.f, 0.f, 0.f};
  for (int r = r0 + rl; r < r0 + rowsPer; r += 16) {
    size_t i = (size_t)r * N + col4;
    floatx4 v = bs;
    for (int k = 0; k < S; ++k) v += *(const floatx4*)(Cp + k * stride + i);
    *(floatx4*)(Y + i) = v;
    s += v;
    qq += v * v;
  }
  __shared__ floatx4 ls[16][16], lq[16][16];
  ls[rl][cg] = s;
  lq[rl][cg] = qq;
  __syncthreads();
  if (t < 16) {
    floatx4 S4 = {0.f, 0.f, 0.f, 0.f}, Q4 = {0.f, 0.f, 0.f, 0.f};
#pragma unroll
    for (int r = 0; r < 16; ++r) {
      S4 += ls[r][t];
      Q4 += lq[r][t];
    }
    size_t o = (size_t)blockIdx.y * N + blockIdx.x * 64 + t * 4;
    *(floatx4*)(psum + o) = S4;
    *(floatx4*)(psq + o) = Q4;
  }
}

// ---- BN finalize+apply (+res, relu) + f16 hi/lo split; float4/half4 ----
__global__ __launch_bounds__(256)
void bn_apply_v(const float* __restrict__ Y, const float* __restrict__ psum,
                const float* __restrict__ psq, const float* __restrict__ g,
                const float* __restrict__ be, const float* __restrict__ res,
                float* __restrict__ outf, _Float16* __restrict__ oh,
                _Float16* __restrict__ ol, int RB, float invM) {
  const int N = 1024;
  const int t = threadIdx.x;
  const int cg = t & 63, rl = t >> 6;
  const int col4 = blockIdx.x * 256 + cg * 4;
  __shared__ floatx4 lA[64], lB[64];
  if (t < 64) {
    int c4 = blockIdx.x * 256 + t * 4;
    floatx4 s = {0.f, 0.f, 0.f, 0.f}, qq = {0.f, 0.f, 0.f, 0.f};
    for (int rb = 0; rb < RB; ++rb) {
      s += *(const floatx4*)(psum + (size_t)rb * N + c4);
      qq += *(const floatx4*)(psq + (size_t)rb * N + c4);
    }
    floatx4 m = s * invM;
    floatx4 var = qq * invM - m * m;
    floatx4 rstd;
#pragma unroll
    for (int i = 0; i < 4; ++i) rstd[i] = rsqrtf(var[i] + 1e-5f);
    floatx4 a = (*(const floatx4*)(g + c4)) * rstd;
    lA[t] = a;
    lB[t] = (*(const floatx4*)(be + c4)) - m * a;
  }
  __syncthreads();
  const floatx4 a = lA[cg], b2 = lB[cg];
#pragma unroll
  for (int rr = 0; rr < 2; ++rr) {
    const int r = blockIdx.y * 8 + rl + rr * 4;
    const size_t i = (size_t)r * N + col4;
    floatx4 v = (*(const floatx4*)(Y + i)) * a + b2;
    if (res) v += *(const floatx4*)(res + i);
#pragma unroll
    for (int ii = 0; ii < 4; ++ii) v[ii] = fmaxf(v[ii], 0.f);
    if (outf) *(floatx4*)(outf + i) = v;
    half4_t h, l;
#pragma unroll
    for (int ii = 0; ii < 4; ++ii) {
      _Float16 hh = (_Float16)v[ii];
      h[ii] = hh;
      l[ii] = (_Float16)((v[ii] - (float)hh) * LO_SCALE);
    }
    *(half4_t*)(oh + i) = h;
    *(half4_t*)(ol + i) = l;
  }
}

// ---- polar projection (== U@Vh from SVD) * sign(det), fused with head
//      split-K reduce + bias and the betas/camera tail copy ----
__device__ __forceinline__ void cofactor3(const float X[9], float C[9]) {
  C[0] = X[4] * X[8] - X[5] * X[7];
  C[1] = X[5] * X[6] - X[3] * X[8];
  C[2] = X[3] * X[7] - X[4] * X[6];
  C[3] = X[2] * X[7] - X[1] * X[8];
  C[4] = X[0] * X[8] - X[2] * X[6];
  C[5] = X[1] * X[6] - X[0] * X[7];
  C[6] = X[1] * X[5] - X[2] * X[4];
  C[7] = X[2] * X[3] - X[0] * X[5];
  C[8] = X[0] * X[4] - X[1] * X[3];
}

__global__ __launch_bounds__(256)
void polar_tail(const float* __restrict__ Cp, const float* __restrict__ bias,
                float* __restrict__ out, int Bt, int nmat, int S,
                size_t stride) {
  const int ldy = 256;
  int idx = blockIdx.x * blockDim.x + threadIdx.x;
  if (idx < nmat) {
    int s = idx / 24, j = idx % 24;
    const size_t base = (size_t)s * ldy + j * 9;
    float A[9], X[9];
#pragma unroll
    for (int k = 0; k < 9; ++k) {
      float v = bias[j * 9 + k];
      for (int z = 0; z < S; ++z) v += Cp[z * stride + base + k];
      A[k] = v;
      X[k] = v;
    }
    double detA = (double)A[0] * ((double)A[4] * A[8] - (double)A[5] * A[7]) -
                  (double)A[1] * ((double)A[3] * A[8] - (double)A[5] * A[6]) +
                  (double)A[2] * ((double)A[3] * A[7] - (double)A[4] * A[6]);
    float sgn = (detA < 0.0) ? -1.f : 1.f;
#pragma unroll 1
    for (int it = 0; it < 12; ++it) {
      float C[9];
      cofactor3(X, C);
      float det = X[0] * C[0] + X[1] * C[1] + X[2] * C[2];
      float ad = fmaxf(fabsf(det), 1e-30f);
      float idet = (det < 0.f ? -1.f : 1.f) / ad;
      float n1 = 0.f, n2 = 0.f;
#pragma unroll
      for (int k = 0; k < 9; ++k) {
        n1 += X[k] * X[k];
        n2 += C[k] * C[k];
      }
      n1 = fmaxf(n1, 1e-30f);
      float zeta = sqrtf(sqrtf(n2 * idet * idet / n1));
      zeta = fminf(fmaxf(zeta, 1e-4f), 1e4f);
      float iz = 0.5f / zeta;
      float hz = 0.5f * zeta;
#pragma unroll
      for (int k = 0; k < 9; ++k) X[k] = hz * X[k] + iz * idet * C[k];
    }
    float* o = out + (size_t)idx * 9;
#pragma unroll
    for (int k = 0; k < 9; ++k) o[k] = X[k] * sgn;
  } else {
    int i = idx - nmat;
    int nb = Bt * 10;
    int nc = Bt * 3;
    int s, k, c;
    if (i < nb) {
      s = i / 10;
      k = i;
      c = 216 + (i % 10);
    } else if (i < nb + nc) {
      int t2 = i - nb;
      s = t2 / 3;
      k = i;
      c = 226 + (t2 % 3);
    } else {
      return;
    }
    float v = bias[c];
    size_t base = (size_t)s * ldy + c;
    for (int z = 0; z < S; ++z) v += Cp[z * stride + base];
    out[(size_t)Bt * 216 + k] = v;
  }
}

// ---------------------------------------------------------------------------
extern "C" void kernel_launch(void* const* d_in, const int* in_sizes, int n_in,
                              void* d_out, int out_size, void* d_ws,
                              size_t ws_size, hipStream_t stream) {
  const float* x = (const float*)d_in[0];
  const float* w1 = (const float*)d_in[1];
  const float* b1 = (const float*)d_in[2];
  const float* g1 = (const float*)d_in[3];
  const float* be1 = (const float*)d_in[4];
  const float* w2a = (const float*)d_in[5];
  const float* b2a = (const float*)d_in[6];
  const float* g2a = (const float*)d_in[7];
  const float* be2a = (const float*)d_in[8];
  const float* w2b = (const float*)d_in[9];
  const float* b2b = (const float*)d_in[10];
  const float* g2b = (const float*)d_in[11];
  const float* be2b = (const float*)d_in[12];
  const float* w3a = (const float*)d_in[13];
  const float* b3a = (const float*)d_in[14];
  const float* g3a = (const float*)d_in[15];
  const float* be3a = (const float*)d_in[16];
  const float* w3b = (const float*)d_in[17];
  const float* b3b = (const float*)d_in[18];
  const float* g3b = (const float*)d_in[19];
  const float* be3b = (const float*)d_in[20];
  const float* w4 = (const float*)d_in[21];
  const float* b4 = (const float*)d_in[22];
  float* out = (float*)d_out;

  const int B = 4096, IN = 10338, INP = 10368, H = 1024;
  const int OUTN = 229, OUTP = 256;
  const int RB = 32;
  const int S_L1 = 2, S_HEAD = 8;

  char* p = (char*)d_ws;
  auto alloc = [&](size_t bytes) -> void* {
    void* r = (void*)p;
    p += (bytes + 255) & ~(size_t)255;
    return r;
  };
  // Cpart arena: 4 x B*H slices. Layer-1 split-K=2 uses slices {0,1};
  // Y = slice 2, Hf = slice 3 (disjoint). Head's 8 x B*OUTP partials
  // (33.5 MB) fit exactly in slices {0,1}, reused after layer 1.
  float* Cpart = (float*)alloc((size_t)4 * B * H * 4);
  float* Y = Cpart + 2 * (size_t)B * H;
  float* Hf = Cpart + 3 * (size_t)B * H;
  _Float16* xh = (_Float16*)alloc((size_t)B * INP * 2);
  _Float16* xl = (_Float16*)alloc((size_t)B * INP * 2);
  _Float16* w1h = (_Float16*)alloc((size_t)H * INP * 2);
  _Float16* w1l = (_Float16*)alloc((size_t)H * INP * 2);
  _Float16 *wmh[4], *wml[4];
  for (int i = 0; i < 4; ++i) {
    wmh[i] = (_Float16*)alloc((size_t)H * H * 2);
    wml[i] = (_Float16*)alloc((size_t)H * H * 2);
  }
  _Float16* w4h = (_Float16*)alloc((size_t)OUTP * H * 2);
  _Float16* w4l = (_Float16*)alloc((size_t)OUTP * H * 2);
  _Float16* hh = (_Float16*)alloc((size_t)B * H * 2);
  _Float16* hl = (_Float16*)alloc((size_t)B * H * 2);
  float* psum = (float*)alloc((size_t)RB * H * 4);
  float* psq = (float*)alloc((size_t)RB * H * 4);

  // ---- conversions (one kernel) ----
  {
    CJobs J;
    const float* wsrc[6] = {w1, w2a, w2b, w3a, w3b, w4};
    _Float16* th[6] = {w1h, wmh[0], wmh[1], wmh[2], wmh[3], w4h};
    _Float16* tl[6] = {w1l, wml[0], wml[1], wml[2], wml[3], w4l};
    int Ks[6] = {IN, H, H, H, H, H};
    int Ns[6] = {H, H, H, H, H, OUTN};
    int Kpads[6] = {INP, H, H, H, H, H};
    int Npads[6] = {H, H, H, H, H, OUTP};
    int start = 0;
    for (int i = 0; i < 6; ++i) {
      J.j[i].src = wsrc[i];
      J.j[i].th = th[i];
      J.j[i].tl = tl[i];
      J.j[i].K = Ks[i];
      J.j[i].N = Ns[i];
      J.j[i].Kpad = Kpads[i];
      J.j[i].tK = Kpads[i] / 32;
      J.j[i].start = start;
      start += (Kpads[i] / 32) * (Npads[i] / 32);
    }
    J.x = x;
    J.xh = xh;
    J.xl = xl;
    J.splitStart = start;
    int total = start + (B * INP / 8 + 255) / 256;
    convert_all<<<dim3(total), 256, 0, stream>>>(J);
  }

  auto bnapply = [&](const float* g, const float* be, const float* res,
                     float* outf) {
    bn_apply_v<<<dim3(H / 256, B / 8), 256, 0, stream>>>(
        Y, psum, psq, g, be, res, outf, hh, hl, RB, 1.f / B);
  };
  // mid GEMM: 128x64 tile, 512 blocks = 2/CU; bias+stats fused, writes Y
  auto midgemm = [&](const _Float16* Bh, const _Float16* Bl,
                     const float* bias) {
    gemm_mid<<<dim3(B / 128, H / 64, 1), 256, 0, stream>>>(
        hh, hl, Bh, Bl, Y, H, H, H, bias, psum, psq);
  };

  // layer 1 (big): R7-proven 128^2 split-K=2, 512 blocks = 2/CU
  gemm_sk<0, false><<<dim3(B / 128, H / 128, S_L1), 256, 0, stream>>>(
      xh, xl, w1h, w1l, Cpart, INP, H, INP / S_L1, (size_t)B * H, nullptr,
      nullptr, nullptr);
  reduce_bias_stats_v<<<dim3(16, RB), 256, 0, stream>>>(
      Cpart, b1, Y, psum, psq, S_L1, (size_t)B * H, B / RB);
  bnapply(g1, be1, nullptr, Hf);
  // resblock 2
  midgemm(wmh[0], wml[0], b2a);
  bnapply(g2a, be2a, nullptr, nullptr);
  midgemm(wmh[1], wml[1], b2b);
  bnapply(g2b, be2b, Hf, Hf);
  // resblock 3
  midgemm(wmh[2], wml[2], b3a);
  bnapply(g3a, be3a, nullptr, nullptr);
  midgemm(wmh[3], wml[3], b3b);
  bnapply(g3b, be3b, Hf, Hf);
  // head: split-K=8, reduce fused into polar_tail
  gemm_sk<2, false><<<dim3(B / 128, OUTP / 128, S_HEAD), 256, 0, stream>>>(
      hh, hl, w4h, w4l, Cpart, H, OUTP, H / S_HEAD, (size_t)B * OUTP, nullptr,
      nullptr, nullptr);

  int nmat = B * 24;
  int ntot = nmat + B * 13;
  polar_tail<<<dim3((ntot + 255) / 256), 256, 0, stream>>>(
      Cpart, b4, out, B, nmat, S_HEAD, (size_t)B * OUTP);
}